// Round 1
// baseline (1826.772 us; speedup 1.0000x reference)
//
#include <hip/hip_runtime.h>
#include <math.h>

#define B_    2
#define NB_   512
#define C_    80
#define FEAT_ 1024
#define FN_   128
#define FC_   128
#define PE_   64
#define G_    16
#define DQ_   64
#define EO_   8
#define NT_   3
#define CC_   16
#define SCALE_CLAMP_ 4.135166556742356f

// ---- workspace layout (float offsets) ----
#define O_ROIEMB  ((size_t)0)                                   // 1024*128
#define O_RANKF   (O_ROIEMB + (size_t)(B_*NB_)*FC_)             // 128*128
#define O_RANKIDX (O_RANKF + (size_t)FN_*FC_)                   // B*128*80 (int)
#define O_SSCORE  (O_RANKIDX + (size_t)B_*FN_*C_)               // B*128*80
#define O_SBOX    (O_SSCORE + (size_t)B_*FN_*C_)                // B*128*80*4
#define O_EMB     (O_SBOX + (size_t)B_*FN_*C_*4)                // B*128*80*128
#define O_EMBT    (O_EMB + (size_t)B_*FN_*C_*FC_)               // B*80*128*128
#define O_ATT     (O_EMBT + (size_t)B_*FN_*C_*FC_)              // B*128*80*128
#define O_LAFF    (O_ATT + (size_t)B_*FN_*C_*FC_)               // 16*16*128*128

// ============ roi_emb = roi_feat @ roi_w + roi_b ============
__global__ __launch_bounds__(128) void k_roi_emb(const float* __restrict__ roi_feat,
                                                 const float* __restrict__ roi_w,
                                                 const float* __restrict__ roi_b,
                                                 float* __restrict__ roi_emb)
{
    __shared__ float row[FEAT_];
    int r = blockIdx.x;
    for (int i = threadIdx.x; i < FEAT_; i += 128) row[i] = roi_feat[(size_t)r*FEAT_ + i];
    __syncthreads();
    int j = threadIdx.x;
    float acc = 0.f;
    for (int k = 0; k < FEAT_; ++k) acc += row[k] * roi_w[(size_t)k*FC_ + j];
    roi_emb[(size_t)r*FC_ + j] = acc + roi_b[j];
}

// ============ rank_feat = sinusoid(FIRST_N,FEAT) @ rank_w + rank_b ============
__global__ __launch_bounds__(128) void k_rank_feat(const float* __restrict__ rank_w,
                                                   const float* __restrict__ rank_b,
                                                   float* __restrict__ rank_feat)
{
    __shared__ float emb[FEAT_];
    int n = blockIdx.x;
    for (int i = threadIdx.x; i < FEAT_/2; i += 128) {
        float dim = powf(1000.0f, (2.0f/(float)FEAT_) * (float)i);
        float dv = (float)n / dim;
        emb[i] = sinf(dv);
        emb[i + FEAT_/2] = cosf(dv);
    }
    __syncthreads();
    int j = threadIdx.x;
    float acc = 0.f;
    for (int k = 0; k < FEAT_; ++k) acc += emb[k] * rank_w[(size_t)k*FC_ + j];
    rank_feat[(size_t)n*FC_ + j] = acc + rank_b[j];
}

// ============ per-(b,c): softmax over 512 boxes + stable top-128 rank ============
__global__ __launch_bounds__(512) void k_topk(const float* __restrict__ scores,
                                              int* __restrict__ rank_idx,
                                              float* __restrict__ sorted_score)
{
    int b = blockIdx.x / C_, c = blockIdx.x % C_;
    __shared__ float p[NB_];
    __shared__ float red[NB_];
    int i = threadIdx.x;
    float s = scores[(size_t)(b*NB_ + i)*(C_+1) + c];
    red[i] = s; __syncthreads();
    for (int o = 256; o > 0; o >>= 1) { if (i < o) red[i] = fmaxf(red[i], red[i+o]); __syncthreads(); }
    float mx = red[0]; __syncthreads();
    float e = expf(s - mx);
    red[i] = e; __syncthreads();
    for (int o = 256; o > 0; o >>= 1) { if (i < o) red[i] += red[i+o]; __syncthreads(); }
    float sum = red[0]; __syncthreads();
    float pi = e / sum;
    p[i] = pi; __syncthreads();
    int rank = 0;
    for (int j = 0; j < NB_; ++j) {
        float pj = p[j];
        rank += (pj > pi) || (pj == pi && j < i);
    }
    if (rank < FN_) {
        rank_idx[(size_t)(b*FN_ + rank)*C_ + c] = i;
        sorted_score[(size_t)(b*FN_ + rank)*C_ + c] = pi;
    }
}

// ============ gather emb_feat + refined sorted boxes ============
__global__ __launch_bounds__(128) void k_gather(const int* __restrict__ rank_idx,
                                                const float* __restrict__ roi_emb,
                                                const float* __restrict__ rank_feat,
                                                const float* __restrict__ pdeltas,
                                                const float* __restrict__ pboxes,
                                                float* __restrict__ emb_feat,
                                                float* __restrict__ sorted_boxes)
{
    int item = blockIdx.x;          // (b*128+n)*80 + c
    int c = item % C_;
    int bn = item / C_;
    int n = bn & (FN_-1);
    int b = bn >> 7;
    int idx = rank_idx[item];
    int row = b*NB_ + idx;
    int d = threadIdx.x;
    emb_feat[(size_t)item*FC_ + d] = roi_emb[(size_t)row*FC_ + d] + rank_feat[(size_t)n*FC_ + d];
    if (d == 0) {
        float x1 = pboxes[row*4+0], y1 = pboxes[row*4+1], x2 = pboxes[row*4+2], y2 = pboxes[row*4+3];
        float w = x2 - x1, h = y2 - y1;
        float cx = x1 + 0.5f*w, cy = y1 + 0.5f*h;
        const float* dl = pdeltas + (size_t)row*(C_*4) + c*4;
        float dx = dl[0]/10.0f, dy = dl[1]/10.0f;
        float dw = fminf(dl[2]/5.0f, SCALE_CLAMP_);
        float dh = fminf(dl[3]/5.0f, SCALE_CLAMP_);
        float pcx = dx*w + cx, pcy = dy*h + cy;
        float pw = expf(dw)*w, ph = expf(dh)*h;
        float* ob = sorted_boxes + (size_t)item*4;
        ob[0] = pcx - 0.5f*pw; ob[1] = pcy - 0.5f*ph;
        ob[2] = pcx + 0.5f*pw; ob[3] = pcy + 0.5f*ph;
    }
}

// ============ transpose emb_feat (B,N,C,D) -> embT (B,C,D,N) ============
__global__ __launch_bounds__(256) void k_transpose(const float* __restrict__ emb,
                                                   float* __restrict__ embT)
{
    int b = blockIdx.x / C_, c = blockIdx.x % C_;
    __shared__ float tile[32][FN_+1];
    const float* src = emb + ((size_t)b*FN_*C_ + c)*FC_;
    float* dst = embT + ((size_t)(b*C_ + c))*FC_*FN_;
    for (int dt = 0; dt < 4; ++dt) {
        for (int i = threadIdx.x; i < FN_*32; i += 256) {
            int nn = i >> 5, dd = i & 31;
            tile[dd][nn] = src[(size_t)nn*C_*FC_ + dt*32 + dd];
        }
        __syncthreads();
        for (int i = threadIdx.x; i < 32*FN_; i += 256) {
            int dd = i >> 7, nn = i & 127;
            dst[(size_t)(dt*32+dd)*FN_ + nn] = tile[dd][nn];
        }
        __syncthreads();
    }
}

// ============ positional log-prior: logaffw[cl,g,n,m] for class chunk ============
__global__ __launch_bounds__(128) void k_pos(const float* __restrict__ sorted_boxes,
                                             const float* __restrict__ pos_w,
                                             const float* __restrict__ pos_b,
                                             float* __restrict__ logaffw,
                                             int b, int c0)
{
    int blk = blockIdx.x;
    int n  = blk & (FN_-1);
    int cl = blk >> 7;
    int c  = c0 + cl;
    int t  = threadIdx.x;
    __shared__ float pw[PE_*G_];
    __shared__ float pb[G_];
    __shared__ float geom[FN_][4];
    for (int i = t; i < PE_*G_; i += 128) pw[i] = pos_w[i];
    if (t < G_) pb[t] = pos_b[t];
    {
        const float* bx = sorted_boxes + (((size_t)(b*FN_ + t))*C_ + c)*4;
        float x1 = bx[0], y1 = bx[1], x2 = bx[2], y2 = bx[3];
        geom[t][0] = 0.5f*(x1+x2);
        geom[t][1] = 0.5f*(y1+y2);
        geom[t][2] = x2 - x1 + 1.0f;
        geom[t][3] = y2 - y1 + 1.0f;
    }
    __syncthreads();
    float cxn = geom[n][0], cyn = geom[n][1], wn = geom[n][2], hn = geom[n][3];
    int m = t;
    float pm[4];
    pm[0] = logf(fmaxf(fabsf((cxn - geom[m][0]) / wn), 1e-3f)) * 100.0f;
    pm[1] = logf(fmaxf(fabsf((cyn - geom[m][1]) / hn), 1e-3f)) * 100.0f;
    pm[2] = logf(wn / geom[m][2]) * 100.0f;
    pm[3] = logf(hn / geom[m][3]) * 100.0f;
    float acc[G_];
    #pragma unroll
    for (int g = 0; g < G_; ++g) acc[g] = pb[g];
    #pragma unroll
    for (int r = 0; r < 8; ++r) {
        float dimr = powf(1000.0f, 0.125f*(float)r);
        #pragma unroll
        for (int ff = 0; ff < 4; ++ff) {
            float v = pm[ff] / dimr;
            float sv = sinf(v), cv = cosf(v);
            const float* ws_ = &pw[(ff*16 + r)*G_];
            const float* wc_ = &pw[(ff*16 + 8 + r)*G_];
            #pragma unroll
            for (int g = 0; g < G_; ++g) acc[g] += sv*ws_[g] + cv*wc_[g];
        }
    }
    size_t base = (((size_t)cl*G_)*FN_ + n)*FN_ + m;
    #pragma unroll
    for (int g = 0; g < G_; ++g) {
        float w = fmaxf(acc[g], 0.0f);
        logaffw[base + (size_t)g*(FN_*FN_)] = logf(fmaxf(w, 1e-6f));
    }
}

// ============ attention per (class-in-chunk, group) ============
__global__ __launch_bounds__(512) void k_attn(const float* __restrict__ embT,
                                              const float* __restrict__ q_w, const float* __restrict__ q_b,
                                              const float* __restrict__ k_w, const float* __restrict__ k_b,
                                              const float* __restrict__ out_w, const float* __restrict__ out_b,
                                              const float* __restrict__ logaffw,
                                              float* __restrict__ att,
                                              int b, int c0)
{
    const int g  = blockIdx.x & (G_-1);
    const int cl = blockIdx.x >> 4;
    const int c  = c0 + cl;
    const int t  = threadIdx.x;

    __shared__ float ft[FC_][132];   // [feature d][n]
    __shared__ float qg[FN_][68];    // [n][dq]
    __shared__ float kg[FN_][68];    // [m][dq]
    __shared__ float aff[32][FC_];   // scores chunk, reused as ov buffer

    // ---- load ft
    {
        const float* src = embT + ((size_t)(b*C_ + c))*FC_*FN_;
        for (int i = t; i < FC_*FN_/4; i += 512) {
            int dd = i >> 5, n4 = i & 31;
            float4 v = *(const float4*)(src + (size_t)dd*FN_ + 4*n4);
            *(float4*)&ft[dd][4*n4] = v;
        }
    }
    __syncthreads();

    // ---- qg, kg  (tile: 4 consecutive n x 4 consecutive dq per thread)
    {
        const int n0  = (t & 31) * 4;
        const int dd0 = (t >> 5) * 4;
        const float* wqp = q_w + (size_t)g*DQ_ + dd0;
        const float* wkp = k_w + (size_t)g*DQ_ + dd0;
        float aq[4][4] = {}, ak[4][4] = {};
        for (int j = 0; j < FC_; ++j) {
            float4 fv = *(const float4*)&ft[j][n0];
            float4 wq = *(const float4*)(wqp + (size_t)j*1024);
            float4 wk = *(const float4*)(wkp + (size_t)j*1024);
            float fa[4]  = {fv.x, fv.y, fv.z, fv.w};
            float wqa[4] = {wq.x, wq.y, wq.z, wq.w};
            float wka[4] = {wk.x, wk.y, wk.z, wk.w};
            #pragma unroll
            for (int i = 0; i < 4; ++i)
                #pragma unroll
                for (int jj = 0; jj < 4; ++jj) {
                    aq[i][jj] += fa[i]*wqa[jj];
                    ak[i][jj] += fa[i]*wka[jj];
                }
        }
        float4 qb = *(const float4*)(q_b + g*DQ_ + dd0);
        float4 kb = *(const float4*)(k_b + g*DQ_ + dd0);
        #pragma unroll
        for (int i = 0; i < 4; ++i) {
            *(float4*)&qg[n0+i][dd0] = make_float4(aq[i][0]+qb.x, aq[i][1]+qb.y, aq[i][2]+qb.z, aq[i][3]+qb.w);
            *(float4*)&kg[n0+i][dd0] = make_float4(ak[i][0]+kb.x, ak[i][1]+kb.y, ak[i][2]+kb.z, ak[i][3]+kb.w);
        }
    }
    __syncthreads();

    const float* lwbase = logaffw + ((size_t)(cl*G_ + g))*FN_*FN_;

    for (int ch = 0; ch < 4; ++ch) {
        const int nb = ch*32;
        // ---- aff[nn][m] = qg[nb+nn] . kg[m]   (2 nn x 4 strided m per thread)
        {
            const int nn0 = (t >> 5) * 2;
            const int m0  = (t & 31);
            float acc[2][4] = {};
            for (int d4 = 0; d4 < 16; ++d4) {
                float4 q0 = *(const float4*)&qg[nb+nn0  ][4*d4];
                float4 q1 = *(const float4*)&qg[nb+nn0+1][4*d4];
                #pragma unroll
                for (int i = 0; i < 4; ++i) {
                    float4 kv = *(const float4*)&kg[m0+32*i][4*d4];
                    acc[0][i] += q0.x*kv.x + q0.y*kv.y + q0.z*kv.z + q0.w*kv.w;
                    acc[1][i] += q1.x*kv.x + q1.y*kv.y + q1.z*kv.z + q1.w*kv.w;
                }
            }
            #pragma unroll
            for (int i = 0; i < 4; ++i) {
                aff[nn0  ][m0+32*i] = acc[0][i];
                aff[nn0+1][m0+32*i] = acc[1][i];
            }
        }
        __syncthreads();
        // ---- softmax rows (16 threads/row)
        {
            const int row = t >> 4;
            const int l   = t & 15;
            const float* lw = lwbase + (size_t)(nb+row)*FN_;
            float v[8]; float mx = -INFINITY;
            #pragma unroll
            for (int k2 = 0; k2 < 8; ++k2) {
                int m = l + (k2 << 4);
                v[k2] = aff[row][m]*0.125f + lw[m];
                mx = fmaxf(mx, v[k2]);
            }
            #pragma unroll
            for (int s = 1; s < 16; s <<= 1) mx = fmaxf(mx, __shfl_xor(mx, s, 16));
            float sum = 0.f;
            #pragma unroll
            for (int k2 = 0; k2 < 8; ++k2) { v[k2] = expf(v[k2]-mx); sum += v[k2]; }
            #pragma unroll
            for (int s = 1; s < 16; s <<= 1) sum += __shfl_xor(sum, s, 16);
            #pragma unroll
            for (int k2 = 0; k2 < 8; ++k2) {
                int m = l + (k2 << 4);
                aff[row][m] = v[k2]/sum;
            }
        }
        __syncthreads();
        // ---- ov[nn][d] = sum_m aff[nn][m]*ft[d][m]   (2 nn x 4 strided d per thread)
        float ov[2][4];
        const int nn0 = (t >> 5) * 2;
        const int dj0 = (t & 31);
        {
            #pragma unroll
            for (int i = 0; i < 2; ++i)
                #pragma unroll
                for (int j = 0; j < 4; ++j) ov[i][j] = 0.f;
            for (int m4 = 0; m4 < 32; ++m4) {
                float4 a0 = *(const float4*)&aff[nn0  ][4*m4];
                float4 a1 = *(const float4*)&aff[nn0+1][4*m4];
                #pragma unroll
                for (int j = 0; j < 4; ++j) {
                    float4 fv = *(const float4*)&ft[dj0+32*j][4*m4];
                    ov[0][j] += a0.x*fv.x + a0.y*fv.y + a0.z*fv.z + a0.w*fv.w;
                    ov[1][j] += a1.x*fv.x + a1.y*fv.y + a1.z*fv.z + a1.w*fv.w;
                }
            }
        }
        __syncthreads();   // all aff reads done before overwrite
        {
            #pragma unroll
            for (int j = 0; j < 4; ++j) {
                aff[nn0  ][dj0+32*j] = ov[0][j];
                aff[nn0+1][dj0+32*j] = ov[1][j];
            }
        }
        __syncthreads();
        // ---- lin: att slice [nn][e] = sum_d ov[nn][d]*out_w[g][d][e] + out_b
        if (t < 256) {
            const int nn = t >> 3;
            const int e  = t & 7;
            const float* ow = out_w + ((size_t)g*FC_)*EO_ + e;
            float acc = 0.f;
            for (int d = 0; d < FC_; ++d) acc += aff[nn][d] * ow[(size_t)d*EO_];
            att[(((size_t)(b*FN_ + nb + nn))*C_ + c)*FC_ + g*EO_ + e] = acc + out_b[g*EO_ + e];
        }
        __syncthreads();
    }
}

// ============ final: relu(emb+att) @ logit_w + b -> sigmoid * score ============
__global__ __launch_bounds__(128) void k_final(const float* __restrict__ emb_feat,
                                               const float* __restrict__ att,
                                               const float* __restrict__ logit_w,
                                               const float* __restrict__ logit_b,
                                               const float* __restrict__ sorted_score,
                                               float* __restrict__ out)
{
    int item = blockIdx.x;
    int d = threadIdx.x;
    __shared__ float af[FC_];
    float v = emb_feat[(size_t)item*FC_ + d] + att[(size_t)item*FC_ + d];
    af[d] = fmaxf(v, 0.f);
    __syncthreads();
    if (d < NT_) {
        float acc = logit_b[d];
        for (int k = 0; k < FC_; ++k) acc += af[k] * logit_w[(size_t)k*NT_ + d];
        float s = 1.f / (1.f + expf(-acc));
        out[(size_t)item*NT_ + d] = s * sorted_score[item];
    }
}

extern "C" void kernel_launch(void* const* d_in, const int* in_sizes, int n_in,
                              void* d_out, int out_size, void* d_ws, size_t ws_size,
                              hipStream_t stream) {
    (void)in_sizes; (void)n_in; (void)out_size; (void)ws_size;
    const float* roi_feat = (const float*)d_in[0];
    const float* scores   = (const float*)d_in[1];
    const float* pdeltas  = (const float*)d_in[2];
    const float* pboxes   = (const float*)d_in[3];
    const float* roi_w    = (const float*)d_in[4];
    const float* roi_b    = (const float*)d_in[5];
    const float* rank_w   = (const float*)d_in[6];
    const float* rank_b   = (const float*)d_in[7];
    const float* logit_w  = (const float*)d_in[8];
    const float* logit_b  = (const float*)d_in[9];
    const float* pos_w    = (const float*)d_in[10];
    const float* pos_b    = (const float*)d_in[11];
    const float* q_w      = (const float*)d_in[12];
    const float* q_b      = (const float*)d_in[13];
    const float* k_w      = (const float*)d_in[14];
    const float* k_b      = (const float*)d_in[15];
    const float* out_w    = (const float*)d_in[16];
    const float* out_b    = (const float*)d_in[17];
    float* ws = (float*)d_ws;

    float* roi_emb      = ws + O_ROIEMB;
    float* rank_feat    = ws + O_RANKF;
    int*   rank_idx     = (int*)(ws + O_RANKIDX);
    float* sorted_score = ws + O_SSCORE;
    float* sorted_boxes = ws + O_SBOX;
    float* emb_feat     = ws + O_EMB;
    float* embT         = ws + O_EMBT;
    float* att          = ws + O_ATT;
    float* logaffw      = ws + O_LAFF;

    k_roi_emb<<<dim3(B_*NB_), dim3(128), 0, stream>>>(roi_feat, roi_w, roi_b, roi_emb);
    k_rank_feat<<<dim3(FN_), dim3(128), 0, stream>>>(rank_w, rank_b, rank_feat);
    k_topk<<<dim3(B_*C_), dim3(512), 0, stream>>>(scores, rank_idx, sorted_score);
    k_gather<<<dim3(B_*FN_*C_), dim3(128), 0, stream>>>(rank_idx, roi_emb, rank_feat,
                                                        pdeltas, pboxes, emb_feat, sorted_boxes);
    k_transpose<<<dim3(B_*C_), dim3(256), 0, stream>>>(emb_feat, embT);

    for (int b = 0; b < B_; ++b) {
        for (int c0 = 0; c0 < C_; c0 += CC_) {
            k_pos<<<dim3(CC_*FN_), dim3(128), 0, stream>>>(sorted_boxes, pos_w, pos_b, logaffw, b, c0);
            k_attn<<<dim3(CC_*G_), dim3(512), 0, stream>>>(embT, q_w, q_b, k_w, k_b,
                                                           out_w, out_b, logaffw, att, b, c0);
        }
    }

    k_final<<<dim3(B_*FN_*C_), dim3(128), 0, stream>>>(emb_feat, att, logit_w, logit_b,
                                                       sorted_score, d_out ? (float*)d_out : nullptr);
}

// Round 2
// 1209.737 us; speedup vs baseline: 1.5101x; 1.5101x over previous
//
#include <hip/hip_runtime.h>
#include <math.h>

#define B_    2
#define NB_   512
#define C_    80
#define FEAT_ 1024
#define FN_   128
#define FC_   128
#define PE_   64
#define G_    16
#define DQ_   64
#define EO_   8
#define NT_   3
#define SCALE_CLAMP_ 4.135166556742356f

// ---- workspace layout (float offsets) ----
#define O_ROIEMB  ((size_t)0)                                   // 1024*128
#define O_RANKF   (O_ROIEMB + (size_t)(B_*NB_)*FC_)             // 128*128
#define O_RANKIDX (O_RANKF + (size_t)FN_*FC_)                   // B*128*80 (int)
#define O_SSCORE  (O_RANKIDX + (size_t)B_*FN_*C_)               // B*128*80
#define O_SBOX    (O_SSCORE + (size_t)B_*FN_*C_)                // B*128*80*4
#define O_EMB     (O_SBOX + (size_t)B_*FN_*C_*4)                // B*128*80*128
#define O_EMBT    (O_EMB + (size_t)B_*FN_*C_*FC_)               // B*80*128*128
#define O_ATT     (O_EMBT + (size_t)B_*FN_*C_*FC_)              // B*128*80*128

// ============ roi_emb = roi_feat @ roi_w + roi_b ============
__global__ __launch_bounds__(128) void k_roi_emb(const float* __restrict__ roi_feat,
                                                 const float* __restrict__ roi_w,
                                                 const float* __restrict__ roi_b,
                                                 float* __restrict__ roi_emb)
{
    __shared__ float row[FEAT_];
    int r = blockIdx.x;
    for (int i = threadIdx.x; i < FEAT_; i += 128) row[i] = roi_feat[(size_t)r*FEAT_ + i];
    __syncthreads();
    int j = threadIdx.x;
    float acc = 0.f;
    for (int k = 0; k < FEAT_; ++k) acc += row[k] * roi_w[(size_t)k*FC_ + j];
    roi_emb[(size_t)r*FC_ + j] = acc + roi_b[j];
}

// ============ rank_feat = sinusoid(FIRST_N,FEAT) @ rank_w + rank_b ============
__global__ __launch_bounds__(128) void k_rank_feat(const float* __restrict__ rank_w,
                                                   const float* __restrict__ rank_b,
                                                   float* __restrict__ rank_feat)
{
    __shared__ float emb[FEAT_];
    int n = blockIdx.x;
    for (int i = threadIdx.x; i < FEAT_/2; i += 128) {
        float dim = powf(1000.0f, (2.0f/(float)FEAT_) * (float)i);
        float dv = (float)n / dim;
        emb[i] = sinf(dv);
        emb[i + FEAT_/2] = cosf(dv);
    }
    __syncthreads();
    int j = threadIdx.x;
    float acc = 0.f;
    for (int k = 0; k < FEAT_; ++k) acc += emb[k] * rank_w[(size_t)k*FC_ + j];
    rank_feat[(size_t)n*FC_ + j] = acc + rank_b[j];
}

// ============ per-(b,c): softmax over 512 boxes + stable top-128 rank ============
__global__ __launch_bounds__(512) void k_topk(const float* __restrict__ scores,
                                              int* __restrict__ rank_idx,
                                              float* __restrict__ sorted_score)
{
    int b = blockIdx.x / C_, c = blockIdx.x % C_;
    __shared__ float p[NB_];
    __shared__ float red[NB_];
    int i = threadIdx.x;
    float s = scores[(size_t)(b*NB_ + i)*(C_+1) + c];
    red[i] = s; __syncthreads();
    for (int o = 256; o > 0; o >>= 1) { if (i < o) red[i] = fmaxf(red[i], red[i+o]); __syncthreads(); }
    float mx = red[0]; __syncthreads();
    float e = expf(s - mx);
    red[i] = e; __syncthreads();
    for (int o = 256; o > 0; o >>= 1) { if (i < o) red[i] += red[i+o]; __syncthreads(); }
    float sum = red[0]; __syncthreads();
    float pi = e / sum;
    p[i] = pi; __syncthreads();
    int rank = 0;
    for (int j = 0; j < NB_; ++j) {
        float pj = p[j];
        rank += (pj > pi) || (pj == pi && j < i);
    }
    if (rank < FN_) {
        rank_idx[(size_t)(b*FN_ + rank)*C_ + c] = i;
        sorted_score[(size_t)(b*FN_ + rank)*C_ + c] = pi;
    }
}

// ============ gather emb_feat + refined sorted boxes ============
__global__ __launch_bounds__(128) void k_gather(const int* __restrict__ rank_idx,
                                                const float* __restrict__ roi_emb,
                                                const float* __restrict__ rank_feat,
                                                const float* __restrict__ pdeltas,
                                                const float* __restrict__ pboxes,
                                                float* __restrict__ emb_feat,
                                                float* __restrict__ sorted_boxes)
{
    int item = blockIdx.x;          // (b*128+n)*80 + c
    int c = item % C_;
    int bn = item / C_;
    int n = bn & (FN_-1);
    int b = bn >> 7;
    int idx = rank_idx[item];
    int row = b*NB_ + idx;
    int d = threadIdx.x;
    emb_feat[(size_t)item*FC_ + d] = roi_emb[(size_t)row*FC_ + d] + rank_feat[(size_t)n*FC_ + d];
    if (d == 0) {
        float x1 = pboxes[row*4+0], y1 = pboxes[row*4+1], x2 = pboxes[row*4+2], y2 = pboxes[row*4+3];
        float w = x2 - x1, h = y2 - y1;
        float cx = x1 + 0.5f*w, cy = y1 + 0.5f*h;
        const float* dl = pdeltas + (size_t)row*(C_*4) + c*4;
        float dx = dl[0]/10.0f, dy = dl[1]/10.0f;
        float dw = fminf(dl[2]/5.0f, SCALE_CLAMP_);
        float dh = fminf(dl[3]/5.0f, SCALE_CLAMP_);
        float pcx = dx*w + cx, pcy = dy*h + cy;
        float pw = expf(dw)*w, ph = expf(dh)*h;
        float* ob = sorted_boxes + (size_t)item*4;
        ob[0] = pcx - 0.5f*pw; ob[1] = pcy - 0.5f*ph;
        ob[2] = pcx + 0.5f*pw; ob[3] = pcy + 0.5f*ph;
    }
}

// ============ transpose emb_feat (B,N,C,D) -> embT (B,C,D,N) ============
__global__ __launch_bounds__(256) void k_transpose(const float* __restrict__ emb,
                                                   float* __restrict__ embT)
{
    int b = blockIdx.x / C_, c = blockIdx.x % C_;
    __shared__ float tile[32][FN_+1];
    const float* src = emb + ((size_t)b*FN_*C_ + c)*FC_;
    float* dst = embT + ((size_t)(b*C_ + c))*FC_*FN_;
    for (int dt = 0; dt < 4; ++dt) {
        for (int i = threadIdx.x; i < FN_*32; i += 256) {
            int nn = i >> 5, dd = i & 31;
            tile[dd][nn] = src[(size_t)nn*C_*FC_ + dt*32 + dd];
        }
        __syncthreads();
        for (int i = threadIdx.x; i < 32*FN_; i += 256) {
            int dd = i >> 7, nn = i & 127;
            dst[(size_t)(dt*32+dd)*FN_ + nn] = tile[dd][nn];
        }
        __syncthreads();
    }
}

// ============ attention per (class, group), pos-prior fused into softmax ============
__global__ __launch_bounds__(512) void k_attn(const float* __restrict__ embT,
                                              const float* __restrict__ q_w, const float* __restrict__ q_b,
                                              const float* __restrict__ k_w, const float* __restrict__ k_b,
                                              const float* __restrict__ out_w, const float* __restrict__ out_b,
                                              const float* __restrict__ sorted_boxes,
                                              const float* __restrict__ pos_w, const float* __restrict__ pos_b,
                                              float* __restrict__ att)
{
    // XCD-friendly decode: the 16 g-blocks of one (b,c) sit at stride 160
    // (same bid mod 8 -> same XCD L2 for shared embT/boxes reads).
    const int g  = blockIdx.x / (B_*C_);
    const int bc = blockIdx.x % (B_*C_);
    const int c  = bc % C_;
    const int b  = bc / C_;
    const int t  = threadIdx.x;

    __shared__ float ft[FC_][132];   // [feature d][n]  67.6 KB
    __shared__ float qg[FN_][68];    // [n][dq]         34.8 KB
    __shared__ float kg[FN_][68];    // [m][dq]         34.8 KB
    __shared__ float aff[32][FC_];   // scores chunk / ov buffer  16.4 KB
    __shared__ float geom[FN_][8];   // cx,cy,w,h,logw,logh        4 KB
    __shared__ float pwg[PE_];       // pos_w[:, g]
    __shared__ float sdim[8];        // 1/1000^(r/8)

    // ---- stage ft + geometry + pos weights
    {
        const float* src = embT + ((size_t)(b*C_ + c))*FC_*FN_;
        for (int i = t; i < FC_*FN_/4; i += 512) {
            int dd = i >> 5, n4 = i & 31;
            float4 v = *(const float4*)(src + (size_t)dd*FN_ + 4*n4);
            *(float4*)&ft[dd][4*n4] = v;
        }
        if (t < FN_) {
            const float* bx = sorted_boxes + (((size_t)(b*FN_ + t))*C_ + c)*4;
            float x1 = bx[0], y1 = bx[1], x2 = bx[2], y2 = bx[3];
            float w = x2 - x1 + 1.0f;
            float h = y2 - y1 + 1.0f;
            geom[t][0] = 0.5f*(x1+x2);
            geom[t][1] = 0.5f*(y1+y2);
            geom[t][2] = w;
            geom[t][3] = h;
            geom[t][4] = logf(w);
            geom[t][5] = logf(h);
        }
        if (t >= 128 && t < 128 + PE_) pwg[t-128] = pos_w[(t-128)*G_ + g];
        if (t >= 192 && t < 200) sdim[t-192] = 1.0f / powf(1000.0f, 0.125f*(float)(t-192));
    }
    const float pbg = pos_b[g];
    __syncthreads();

    // ---- qg, kg  (tile: 4 consecutive n x 4 consecutive dq per thread)
    {
        const int n0  = (t & 31) * 4;
        const int dd0 = (t >> 5) * 4;
        const float* wqp = q_w + (size_t)g*DQ_ + dd0;
        const float* wkp = k_w + (size_t)g*DQ_ + dd0;
        float aq[4][4] = {}, ak[4][4] = {};
        for (int j = 0; j < FC_; ++j) {
            float4 fv = *(const float4*)&ft[j][n0];
            float4 wq = *(const float4*)(wqp + (size_t)j*1024);
            float4 wk = *(const float4*)(wkp + (size_t)j*1024);
            float fa[4]  = {fv.x, fv.y, fv.z, fv.w};
            float wqa[4] = {wq.x, wq.y, wq.z, wq.w};
            float wka[4] = {wk.x, wk.y, wk.z, wk.w};
            #pragma unroll
            for (int i = 0; i < 4; ++i)
                #pragma unroll
                for (int jj = 0; jj < 4; ++jj) {
                    aq[i][jj] += fa[i]*wqa[jj];
                    ak[i][jj] += fa[i]*wka[jj];
                }
        }
        float4 qb = *(const float4*)(q_b + g*DQ_ + dd0);
        float4 kb = *(const float4*)(k_b + g*DQ_ + dd0);
        #pragma unroll
        for (int i = 0; i < 4; ++i) {
            *(float4*)&qg[n0+i][dd0] = make_float4(aq[i][0]+qb.x, aq[i][1]+qb.y, aq[i][2]+qb.z, aq[i][3]+qb.w);
            *(float4*)&kg[n0+i][dd0] = make_float4(ak[i][0]+kb.x, ak[i][1]+kb.y, ak[i][2]+kb.z, ak[i][3]+kb.w);
        }
    }
    __syncthreads();

    for (int ch = 0; ch < 4; ++ch) {
        const int nb = ch*32;
        // ---- aff[nn][m] = qg[nb+nn] . kg[m]   (2 nn x 4 strided m per thread)
        {
            const int nn0 = (t >> 5) * 2;
            const int m0  = (t & 31);
            float acc[2][4] = {};
            for (int d4 = 0; d4 < 16; ++d4) {
                float4 q0 = *(const float4*)&qg[nb+nn0  ][4*d4];
                float4 q1 = *(const float4*)&qg[nb+nn0+1][4*d4];
                #pragma unroll
                for (int i = 0; i < 4; ++i) {
                    float4 kv = *(const float4*)&kg[m0+32*i][4*d4];
                    acc[0][i] += q0.x*kv.x + q0.y*kv.y + q0.z*kv.z + q0.w*kv.w;
                    acc[1][i] += q1.x*kv.x + q1.y*kv.y + q1.z*kv.z + q1.w*kv.w;
                }
            }
            #pragma unroll
            for (int i = 0; i < 4; ++i) {
                aff[nn0  ][m0+32*i] = acc[0][i];
                aff[nn0+1][m0+32*i] = acc[1][i];
            }
        }
        __syncthreads();
        // ---- softmax rows with fused positional log-prior (16 threads/row)
        {
            const int row = t >> 4;
            const int l   = t & 15;
            const int n   = nb + row;
            const float cxn = geom[n][0], cyn = geom[n][1];
            const float rwn = 1.0f / geom[n][2], rhn = 1.0f / geom[n][3];
            const float lwn = geom[n][4], lhn = geom[n][5];
            float v[8]; float mx = -INFINITY;
            #pragma unroll
            for (int k2 = 0; k2 < 8; ++k2) {
                const int m = l + (k2 << 4);
                float pm0 = __logf(fmaxf(fabsf((cxn - geom[m][0]) * rwn), 1e-3f)) * 100.0f;
                float pm1 = __logf(fmaxf(fabsf((cyn - geom[m][1]) * rhn), 1e-3f)) * 100.0f;
                float pm2 = (lwn - geom[m][4]) * 100.0f;
                float pm3 = (lhn - geom[m][5]) * 100.0f;
                float acc = pbg;
                #pragma unroll 1
                for (int r = 0; r < 8; ++r) {
                    float inv = sdim[r];
                    float a0 = pm0 * inv, a1 = pm1 * inv, a2 = pm2 * inv, a3 = pm3 * inv;
                    acc += __sinf(a0)*pwg[r]      + __cosf(a0)*pwg[8+r]
                         + __sinf(a1)*pwg[16+r]   + __cosf(a1)*pwg[24+r]
                         + __sinf(a2)*pwg[32+r]   + __cosf(a2)*pwg[40+r]
                         + __sinf(a3)*pwg[48+r]   + __cosf(a3)*pwg[56+r];
                }
                float lw = __logf(fmaxf(fmaxf(acc, 0.0f), 1e-6f));
                float val = aff[row][m]*0.125f + lw;
                v[k2] = val;
                mx = fmaxf(mx, val);
            }
            #pragma unroll
            for (int s = 1; s < 16; s <<= 1) mx = fmaxf(mx, __shfl_xor(mx, s, 16));
            float sum = 0.f;
            #pragma unroll
            for (int k2 = 0; k2 < 8; ++k2) { v[k2] = __expf(v[k2]-mx); sum += v[k2]; }
            #pragma unroll
            for (int s = 1; s < 16; s <<= 1) sum += __shfl_xor(sum, s, 16);
            float rs = 1.0f / sum;
            #pragma unroll
            for (int k2 = 0; k2 < 8; ++k2) {
                int m = l + (k2 << 4);
                aff[row][m] = v[k2]*rs;
            }
        }
        __syncthreads();
        // ---- ov[nn][d] = sum_m aff[nn][m]*ft[d][m]   (2 nn x 4 strided d per thread)
        float ov[2][4];
        const int nn0 = (t >> 5) * 2;
        const int dj0 = (t & 31);
        {
            #pragma unroll
            for (int i = 0; i < 2; ++i)
                #pragma unroll
                for (int j = 0; j < 4; ++j) ov[i][j] = 0.f;
            for (int m4 = 0; m4 < 32; ++m4) {
                float4 a0 = *(const float4*)&aff[nn0  ][4*m4];
                float4 a1 = *(const float4*)&aff[nn0+1][4*m4];
                #pragma unroll
                for (int j = 0; j < 4; ++j) {
                    float4 fv = *(const float4*)&ft[dj0+32*j][4*m4];
                    ov[0][j] += a0.x*fv.x + a0.y*fv.y + a0.z*fv.z + a0.w*fv.w;
                    ov[1][j] += a1.x*fv.x + a1.y*fv.y + a1.z*fv.z + a1.w*fv.w;
                }
            }
        }
        __syncthreads();   // all aff reads done before overwrite
        {
            #pragma unroll
            for (int j = 0; j < 4; ++j) {
                aff[nn0  ][dj0+32*j] = ov[0][j];
                aff[nn0+1][dj0+32*j] = ov[1][j];
            }
        }
        __syncthreads();
        // ---- lin: att slice [nn][e] = sum_d ov[nn][d]*out_w[g][d][e] + out_b
        if (t < 256) {
            const int nn = t >> 3;
            const int e  = t & 7;
            const float* ow = out_w + ((size_t)g*FC_)*EO_ + e;
            float acc = 0.f;
            for (int d = 0; d < FC_; ++d) acc += aff[nn][d] * ow[(size_t)d*EO_];
            att[(((size_t)(b*FN_ + nb + nn))*C_ + c)*FC_ + g*EO_ + e] = acc + out_b[g*EO_ + e];
        }
        __syncthreads();
    }
}

// ============ final: relu(emb+att) @ logit_w + b -> sigmoid * score ============
__global__ __launch_bounds__(128) void k_final(const float* __restrict__ emb_feat,
                                               const float* __restrict__ att,
                                               const float* __restrict__ logit_w,
                                               const float* __restrict__ logit_b,
                                               const float* __restrict__ sorted_score,
                                               float* __restrict__ out)
{
    int item = blockIdx.x;
    int d = threadIdx.x;
    __shared__ float af[FC_];
    float v = emb_feat[(size_t)item*FC_ + d] + att[(size_t)item*FC_ + d];
    af[d] = fmaxf(v, 0.f);
    __syncthreads();
    if (d < NT_) {
        float acc = logit_b[d];
        for (int k = 0; k < FC_; ++k) acc += af[k] * logit_w[(size_t)k*NT_ + d];
        float s = 1.f / (1.f + expf(-acc));
        out[(size_t)item*NT_ + d] = s * sorted_score[item];
    }
}

extern "C" void kernel_launch(void* const* d_in, const int* in_sizes, int n_in,
                              void* d_out, int out_size, void* d_ws, size_t ws_size,
                              hipStream_t stream) {
    (void)in_sizes; (void)n_in; (void)out_size; (void)ws_size;
    const float* roi_feat = (const float*)d_in[0];
    const float* scores   = (const float*)d_in[1];
    const float* pdeltas  = (const float*)d_in[2];
    const float* pboxes   = (const float*)d_in[3];
    const float* roi_w    = (const float*)d_in[4];
    const float* roi_b    = (const float*)d_in[5];
    const float* rank_w   = (const float*)d_in[6];
    const float* rank_b   = (const float*)d_in[7];
    const float* logit_w  = (const float*)d_in[8];
    const float* logit_b  = (const float*)d_in[9];
    const float* pos_w    = (const float*)d_in[10];
    const float* pos_b    = (const float*)d_in[11];
    const float* q_w      = (const float*)d_in[12];
    const float* q_b      = (const float*)d_in[13];
    const float* k_w      = (const float*)d_in[14];
    const float* k_b      = (const float*)d_in[15];
    const float* out_w    = (const float*)d_in[16];
    const float* out_b    = (const float*)d_in[17];
    float* ws = (float*)d_ws;

    float* roi_emb      = ws + O_ROIEMB;
    float* rank_feat    = ws + O_RANKF;
    int*   rank_idx     = (int*)(ws + O_RANKIDX);
    float* sorted_score = ws + O_SSCORE;
    float* sorted_boxes = ws + O_SBOX;
    float* emb_feat     = ws + O_EMB;
    float* embT         = ws + O_EMBT;
    float* att          = ws + O_ATT;

    k_roi_emb<<<dim3(B_*NB_), dim3(128), 0, stream>>>(roi_feat, roi_w, roi_b, roi_emb);
    k_rank_feat<<<dim3(FN_), dim3(128), 0, stream>>>(rank_w, rank_b, rank_feat);
    k_topk<<<dim3(B_*C_), dim3(512), 0, stream>>>(scores, rank_idx, sorted_score);
    k_gather<<<dim3(B_*FN_*C_), dim3(128), 0, stream>>>(rank_idx, roi_emb, rank_feat,
                                                        pdeltas, pboxes, emb_feat, sorted_boxes);
    k_transpose<<<dim3(B_*C_), dim3(256), 0, stream>>>(emb_feat, embT);

    k_attn<<<dim3(B_*C_*G_), dim3(512), 0, stream>>>(embT, q_w, q_b, k_w, k_b,
                                                     out_w, out_b, sorted_boxes,
                                                     pos_w, pos_b, att);

    k_final<<<dim3(B_*FN_*C_), dim3(128), 0, stream>>>(emb_feat, att, logit_w, logit_b,
                                                       sorted_score, d_out ? (float*)d_out : nullptr);
}

// Round 3
// 972.170 us; speedup vs baseline: 1.8791x; 1.2444x over previous
//
#include <hip/hip_runtime.h>
#include <math.h>

#define B_    2
#define NB_   512
#define C_    80
#define FEAT_ 1024
#define FN_   128
#define FC_   128
#define PE_   64
#define G_    16
#define DQ_   64
#define EO_   8
#define NT_   3
#define CC_   16          // classes per chunk
#define SCALE_CLAMP_ 4.135166556742356f

// ---- workspace layout (float offsets) ----
#define O_ROIEMB  ((size_t)0)                                   // 1024*128
#define O_RANKF   (O_ROIEMB + (size_t)(B_*NB_)*FC_)             // 128*128
#define O_RANKIDX (O_RANKF + (size_t)FN_*FC_)                   // B*128*80 (int)
#define O_SSCORE  (O_RANKIDX + (size_t)B_*FN_*C_)               // B*128*80
#define O_SBOX    (O_SSCORE + (size_t)B_*FN_*C_)                // B*128*80*4
#define O_EMB     (O_SBOX + (size_t)B_*FN_*C_*4)                // B*128*80*128
#define O_EMBT    (O_EMB + (size_t)B_*FN_*C_*FC_)               // B*80*128*128
#define O_ATT     (O_EMBT + (size_t)B_*FN_*C_*FC_)              // B*128*80*128
#define O_LW      (O_ATT + (size_t)B_*FN_*C_*FC_)               // CC*128*16*128 ushort (reused per chunk)

__device__ __forceinline__ float bf2f(unsigned short u) {
    return __uint_as_float(((unsigned int)u) << 16);
}
__device__ __forceinline__ unsigned short f2bf(float f) {
    unsigned int x = __float_as_uint(f);
    unsigned int r = (x + 0x7fff + ((x >> 16) & 1)) >> 16;   // RNE
    return (unsigned short)r;
}

// ============ roi_emb = roi_feat @ roi_w + roi_b ============
__global__ __launch_bounds__(128) void k_roi_emb(const float* __restrict__ roi_feat,
                                                 const float* __restrict__ roi_w,
                                                 const float* __restrict__ roi_b,
                                                 float* __restrict__ roi_emb)
{
    __shared__ float row[FEAT_];
    int r = blockIdx.x;
    for (int i = threadIdx.x; i < FEAT_; i += 128) row[i] = roi_feat[(size_t)r*FEAT_ + i];
    __syncthreads();
    int j = threadIdx.x;
    float acc = 0.f;
    for (int k = 0; k < FEAT_; ++k) acc += row[k] * roi_w[(size_t)k*FC_ + j];
    roi_emb[(size_t)r*FC_ + j] = acc + roi_b[j];
}

// ============ rank_feat ============
__global__ __launch_bounds__(128) void k_rank_feat(const float* __restrict__ rank_w,
                                                   const float* __restrict__ rank_b,
                                                   float* __restrict__ rank_feat)
{
    __shared__ float emb[FEAT_];
    int n = blockIdx.x;
    for (int i = threadIdx.x; i < FEAT_/2; i += 128) {
        float dim = powf(1000.0f, (2.0f/(float)FEAT_) * (float)i);
        float dv = (float)n / dim;
        emb[i] = sinf(dv);
        emb[i + FEAT_/2] = cosf(dv);
    }
    __syncthreads();
    int j = threadIdx.x;
    float acc = 0.f;
    for (int k = 0; k < FEAT_; ++k) acc += emb[k] * rank_w[(size_t)k*FC_ + j];
    rank_feat[(size_t)n*FC_ + j] = acc + rank_b[j];
}

// ============ softmax over boxes + stable top-128 rank ============
__global__ __launch_bounds__(512) void k_topk(const float* __restrict__ scores,
                                              int* __restrict__ rank_idx,
                                              float* __restrict__ sorted_score)
{
    int b = blockIdx.x / C_, c = blockIdx.x % C_;
    __shared__ float p[NB_];
    __shared__ float red[NB_];
    int i = threadIdx.x;
    float s = scores[(size_t)(b*NB_ + i)*(C_+1) + c];
    red[i] = s; __syncthreads();
    for (int o = 256; o > 0; o >>= 1) { if (i < o) red[i] = fmaxf(red[i], red[i+o]); __syncthreads(); }
    float mx = red[0]; __syncthreads();
    float e = expf(s - mx);
    red[i] = e; __syncthreads();
    for (int o = 256; o > 0; o >>= 1) { if (i < o) red[i] += red[i+o]; __syncthreads(); }
    float sum = red[0]; __syncthreads();
    float pi = e / sum;
    p[i] = pi; __syncthreads();
    int rank = 0;
    for (int j = 0; j < NB_; ++j) {
        float pj = p[j];
        rank += (pj > pi) || (pj == pi && j < i);
    }
    if (rank < FN_) {
        rank_idx[(size_t)(b*FN_ + rank)*C_ + c] = i;
        sorted_score[(size_t)(b*FN_ + rank)*C_ + c] = pi;
    }
}

// ============ gather emb_feat + refined sorted boxes ============
__global__ __launch_bounds__(128) void k_gather(const int* __restrict__ rank_idx,
                                                const float* __restrict__ roi_emb,
                                                const float* __restrict__ rank_feat,
                                                const float* __restrict__ pdeltas,
                                                const float* __restrict__ pboxes,
                                                float* __restrict__ emb_feat,
                                                float* __restrict__ sorted_boxes)
{
    int item = blockIdx.x;          // (b*128+n)*80 + c
    int c = item % C_;
    int bn = item / C_;
    int n = bn & (FN_-1);
    int b = bn >> 7;
    int idx = rank_idx[item];
    int row = b*NB_ + idx;
    int d = threadIdx.x;
    emb_feat[(size_t)item*FC_ + d] = roi_emb[(size_t)row*FC_ + d] + rank_feat[(size_t)n*FC_ + d];
    if (d == 0) {
        float x1 = pboxes[row*4+0], y1 = pboxes[row*4+1], x2 = pboxes[row*4+2], y2 = pboxes[row*4+3];
        float w = x2 - x1, h = y2 - y1;
        float cx = x1 + 0.5f*w, cy = y1 + 0.5f*h;
        const float* dl = pdeltas + (size_t)row*(C_*4) + c*4;
        float dx = dl[0]/10.0f, dy = dl[1]/10.0f;
        float dw = fminf(dl[2]/5.0f, SCALE_CLAMP_);
        float dh = fminf(dl[3]/5.0f, SCALE_CLAMP_);
        float pcx = dx*w + cx, pcy = dy*h + cy;
        float pw = expf(dw)*w, ph = expf(dh)*h;
        float* ob = sorted_boxes + (size_t)item*4;
        ob[0] = pcx - 0.5f*pw; ob[1] = pcy - 0.5f*ph;
        ob[2] = pcx + 0.5f*pw; ob[3] = pcy + 0.5f*ph;
    }
}

// ============ transpose emb_feat (B,N,C,D) -> embT (B,C,D,N) ============
__global__ __launch_bounds__(256) void k_transpose(const float* __restrict__ emb,
                                                   float* __restrict__ embT)
{
    int b = blockIdx.x / C_, c = blockIdx.x % C_;
    __shared__ float tile[32][FN_+1];
    const float* src = emb + ((size_t)b*FN_*C_ + c)*FC_;
    float* dst = embT + ((size_t)(b*C_ + c))*FC_*FN_;
    for (int dt = 0; dt < 4; ++dt) {
        for (int i = threadIdx.x; i < FN_*32; i += 256) {
            int nn = i >> 5, dd = i & 31;
            tile[dd][nn] = src[(size_t)nn*C_*FC_ + dt*32 + dd];
        }
        __syncthreads();
        for (int i = threadIdx.x; i < 32*FN_; i += 256) {
            int dd = i >> 7, nn = i & 127;
            dst[(size_t)(dt*32+dd)*FN_ + nn] = tile[dd][nn];
        }
        __syncthreads();
    }
}

// ============ prior w (pre-log, clamped) for all 16 groups, bf16 ============
// grid: CC_*16 blocks (cl = bid>>4, n-chunk of 8 = bid&15), 256 threads.
// lw layout: [cl][n][g][m] bf16
__global__ __launch_bounds__(256) void k_pos2(const float* __restrict__ sorted_boxes,
                                              const float* __restrict__ pos_w,
                                              const float* __restrict__ pos_b,
                                              unsigned short* __restrict__ lw,
                                              int b, int c0)
{
    const int cl  = blockIdx.x >> 4;
    const int n0  = (blockIdx.x & 15) * 8;
    const int c   = c0 + cl;
    const int t   = threadIdx.x;
    const int m   = t & 127;
    const int nh  = t >> 7;

    __shared__ float geomL[FN_][6];
    __shared__ float pwL[PE_*G_];
    __shared__ float pbL[G_];
    __shared__ float sdimL[8];
    __shared__ unsigned short wtile[2*G_*FN_];   // 8 KB

    for (int i = t; i < PE_*G_; i += 256) pwL[i] = pos_w[i];
    if (t < G_) pbL[t] = pos_b[t];
    if (t >= 16 && t < 24) sdimL[t-16] = 1.0f / powf(1000.0f, 0.125f*(float)(t-16));
    if (t < FN_) {
        const float* bx = sorted_boxes + (((size_t)(b*FN_ + t))*C_ + c)*4;
        float x1 = bx[0], y1 = bx[1], x2 = bx[2], y2 = bx[3];
        float w = x2 - x1 + 1.0f;
        float h = y2 - y1 + 1.0f;
        geomL[t][0] = 0.5f*(x1+x2);
        geomL[t][1] = 0.5f*(y1+y2);
        geomL[t][2] = w;
        geomL[t][3] = h;
        geomL[t][4] = __logf(w);
        geomL[t][5] = __logf(h);
    }
    __syncthreads();

    for (int s = 0; s < 4; ++s) {
        const int n = n0 + s*2 + nh;
        float pm[4];
        {
            float cxn = geomL[n][0], cyn = geomL[n][1];
            float rwn = 1.0f/geomL[n][2], rhn = 1.0f/geomL[n][3];
            pm[0] = __logf(fmaxf(fabsf((cxn - geomL[m][0]) * rwn), 1e-3f)) * 100.0f;
            pm[1] = __logf(fmaxf(fabsf((cyn - geomL[m][1]) * rhn), 1e-3f)) * 100.0f;
            pm[2] = (geomL[n][4] - geomL[m][4]) * 100.0f;
            pm[3] = (geomL[n][5] - geomL[m][5]) * 100.0f;
        }
        float acc[G_];
        #pragma unroll
        for (int g = 0; g < G_; ++g) acc[g] = pbL[g];
        #pragma unroll 1
        for (int r = 0; r < 8; ++r) {
            float inv = sdimL[r];
            #pragma unroll
            for (int f = 0; f < 4; ++f) {
                float a = pm[f] * inv;
                float sv, cv;
                __sincosf(a, &sv, &cv);
                const float* ws_ = &pwL[(f*16 + r)*G_];
                const float* wc_ = &pwL[(f*16 + 8 + r)*G_];
                #pragma unroll
                for (int g = 0; g < G_; ++g) acc[g] += sv*ws_[g] + cv*wc_[g];
            }
        }
        #pragma unroll
        for (int g = 0; g < G_; ++g) {
            float w = fmaxf(fmaxf(acc[g], 0.0f), 1e-6f);
            wtile[(nh*G_ + g)*FN_ + m] = f2bf(w);
        }
        __syncthreads();
        // coalesced copy of 2 rows (2*16*128 ushort = 16 KB) to global
        {
            const size_t base4 = ((size_t)(cl*FN_ + n0 + s*2)) * 256;  // float4 units
            const float4* srcv = (const float4*)wtile;
            float4* dstv = (float4*)lw;
            dstv[base4 + t]       = srcv[t];
            dstv[base4 + t + 256] = srcv[t + 256];
        }
        __syncthreads();
    }
}

// ============ attention per (class-in-chunk, group), 1024 threads ============
__global__ __launch_bounds__(1024) void k_attn(const float* __restrict__ embT,
                                               const float* __restrict__ q_w, const float* __restrict__ q_b,
                                               const float* __restrict__ k_w, const float* __restrict__ k_b,
                                               const float* __restrict__ out_w, const float* __restrict__ out_b,
                                               const unsigned short* __restrict__ lw,
                                               float* __restrict__ att,
                                               int b, int c0)
{
    // decode: same (b,c) g-blocks share bid%8 (same XCD L2)
    const int low3 = blockIdx.x & 7;
    const int r8   = blockIdx.x >> 3;
    const int g    = r8 & 15;
    const int cl   = low3 + 8*(r8 >> 4);
    const int c    = c0 + cl;
    const int t    = threadIdx.x;

    __shared__ float ftL[FC_*FN_];      // [d][m-swz]  64 KB
    __shared__ float qkL[2*FN_*DQ_];    // q then k, [n][dq-swz]  64 KB
    __shared__ float affL[32*132];      // 16.9 KB
    __shared__ float redL[256*4];       // 4 KB

    // ---- stage ft swizzled: group(m4) ^= (d&15)
    {
        const float* src = embT + ((size_t)(b*C_ + c))*FC_*FN_;
        for (int i = t; i < FC_*FN_/4; i += 1024) {
            int dd = i >> 5, n4 = i & 31;
            float4 v = *(const float4*)(src + (size_t)dd*FN_ + 4*n4);
            *(float4*)&ftL[dd*FN_ + ((n4 ^ (dd & 15)) << 2)] = v;
        }
    }
    __syncthreads();

    // ---- proj: thread = 4n x 4dq of q OR k
    {
        const int colblk = t >> 5;          // 0..31
        const int isK    = colblk >> 4;     // 0:q 1:k
        const int dqg    = colblk & 15;
        const int dq0    = dqg * 4;
        const int n0     = (t & 31) * 4;
        const float* wb  = (isK ? k_w : q_w) + (size_t)g*DQ_ + dq0;
        const float* bb  = (isK ? k_b : q_b) + g*DQ_ + dq0;
        float acc[4][4] = {};
        for (int j = 0; j < FC_; ++j) {
            float4 fv = *(const float4*)&ftL[j*FN_ + (((n0 >> 2) ^ (j & 15)) << 2)];
            float4 wv = *(const float4*)(wb + (size_t)j*1024);
            float fa[4]  = {fv.x, fv.y, fv.z, fv.w};
            float wa[4]  = {wv.x, wv.y, wv.z, wv.w};
            #pragma unroll
            for (int i = 0; i < 4; ++i)
                #pragma unroll
                for (int jj = 0; jj < 4; ++jj)
                    acc[i][jj] += fa[i]*wa[jj];
        }
        float4 bv = *(const float4*)bb;
        float ba[4] = {bv.x, bv.y, bv.z, bv.w};
        float* dst = qkL + isK*FN_*DQ_;
        #pragma unroll
        for (int i = 0; i < 4; ++i) {
            int nr = n0 + i;
            *(float4*)&dst[nr*DQ_ + ((dqg ^ (nr & 15)) << 2)] =
                make_float4(acc[i][0]+ba[0], acc[i][1]+ba[1], acc[i][2]+ba[2], acc[i][3]+ba[3]);
        }
    }
    __syncthreads();

    const float* qgL = qkL;
    const float* kgL = qkL + FN_*DQ_;

    for (int ch = 0; ch < 4; ++ch) {
        const int nb = ch*32;
        // ---- aff: thread = row(t&31) x 4m strided (broadcast k-reads)
        {
            const int r  = t & 31;
            const int mq = t >> 5;
            const int n  = nb + r;
            float acc4[4] = {};
            for (int d4 = 0; d4 < 16; ++d4) {
                float4 q0 = *(const float4*)&qgL[n*DQ_ + ((d4 ^ (n & 15)) << 2)];
                #pragma unroll
                for (int i = 0; i < 4; ++i) {
                    int mm = mq + 32*i;
                    float4 kv = *(const float4*)&kgL[mm*DQ_ + ((d4 ^ (mm & 15)) << 2)];
                    acc4[i] += q0.x*kv.x + q0.y*kv.y + q0.z*kv.z + q0.w*kv.w;
                }
            }
            #pragma unroll
            for (int i = 0; i < 4; ++i) affL[r*132 + mq + 32*i] = acc4[i];
        }
        __syncthreads();
        // ---- softmax rows: 32 threads/row, log-prior from global bf16
        {
            const int row = t >> 5;
            const int l   = t & 31;
            const unsigned short* lwrow = lw + (((size_t)cl*FN_ + nb + row)*G_ + g)*FN_;
            float v[4]; float mx = -INFINITY;
            #pragma unroll
            for (int k2 = 0; k2 < 4; ++k2) {
                int m = l + (k2 << 5);
                float val = affL[row*132 + m]*0.125f + __logf(bf2f(lwrow[m]));
                v[k2] = val;
                mx = fmaxf(mx, val);
            }
            #pragma unroll
            for (int s = 1; s < 32; s <<= 1) mx = fmaxf(mx, __shfl_xor(mx, s, 32));
            float sum = 0.f;
            #pragma unroll
            for (int k2 = 0; k2 < 4; ++k2) { v[k2] = __expf(v[k2]-mx); sum += v[k2]; }
            #pragma unroll
            for (int s = 1; s < 32; s <<= 1) sum += __shfl_xor(sum, s, 32);
            float rs = 1.0f / sum;
            #pragma unroll
            for (int k2 = 0; k2 < 4; ++k2) affL[row*132 + l + (k2 << 5)] = v[k2]*rs;
        }
        __syncthreads();
        // ---- PV: thread = row(t&31) x 4d strided (broadcast ft-reads)
        float ov4[4] = {};
        {
            const int r  = t & 31;
            const int dg = t >> 5;
            for (int m4 = 0; m4 < 32; ++m4) {
                float4 av = *(const float4*)&affL[r*132 + 4*m4];
                #pragma unroll
                for (int i = 0; i < 4; ++i) {
                    int d = dg + 32*i;
                    float4 fv = *(const float4*)&ftL[d*FN_ + ((m4 ^ (d & 15)) << 2)];
                    ov4[i] += av.x*fv.x + av.y*fv.y + av.z*fv.z + av.w*fv.w;
                }
            }
        }
        __syncthreads();   // all sm reads done
        {
            const int r  = t & 31;
            const int dg = t >> 5;
            #pragma unroll
            for (int i = 0; i < 4; ++i) affL[r*132 + dg + 32*i] = ov4[i];
        }
        __syncthreads();
        // ---- lin with 4-way d-partials
        {
            const int o  = t & 255;
            const int nn = o >> 3;
            const int e  = o & 7;
            const int p  = t >> 8;
            const float* ow = out_w + ((size_t)(g*FC_ + 32*p))*EO_ + e;
            float acc = 0.f;
            #pragma unroll
            for (int d = 0; d < 32; ++d) acc += affL[nn*132 + 32*p + d] * ow[(size_t)d*EO_];
            redL[o*4 + p] = acc;
        }
        __syncthreads();
        if (t < 256) {
            const int nn = t >> 3;
            const int e  = t & 7;
            float4 pr = *(const float4*)&redL[t*4];
            float acc = pr.x + pr.y + pr.z + pr.w + out_b[g*EO_ + e];
            att[(((size_t)(b*FN_ + nb + nn))*C_ + c)*FC_ + g*EO_ + e] = acc;
        }
        __syncthreads();
    }
}

// ============ final ============
__global__ __launch_bounds__(128) void k_final(const float* __restrict__ emb_feat,
                                               const float* __restrict__ att,
                                               const float* __restrict__ logit_w,
                                               const float* __restrict__ logit_b,
                                               const float* __restrict__ sorted_score,
                                               float* __restrict__ out)
{
    int item = blockIdx.x;
    int d = threadIdx.x;
    __shared__ float af[FC_];
    float v = emb_feat[(size_t)item*FC_ + d] + att[(size_t)item*FC_ + d];
    af[d] = fmaxf(v, 0.f);
    __syncthreads();
    if (d < NT_) {
        float acc = logit_b[d];
        for (int k = 0; k < FC_; ++k) acc += af[k] * logit_w[(size_t)k*NT_ + d];
        float s = 1.f / (1.f + expf(-acc));
        out[(size_t)item*NT_ + d] = s * sorted_score[item];
    }
}

extern "C" void kernel_launch(void* const* d_in, const int* in_sizes, int n_in,
                              void* d_out, int out_size, void* d_ws, size_t ws_size,
                              hipStream_t stream) {
    (void)in_sizes; (void)n_in; (void)out_size; (void)ws_size;
    const float* roi_feat = (const float*)d_in[0];
    const float* scores   = (const float*)d_in[1];
    const float* pdeltas  = (const float*)d_in[2];
    const float* pboxes   = (const float*)d_in[3];
    const float* roi_w    = (const float*)d_in[4];
    const float* roi_b    = (const float*)d_in[5];
    const float* rank_w   = (const float*)d_in[6];
    const float* rank_b   = (const float*)d_in[7];
    const float* logit_w  = (const float*)d_in[8];
    const float* logit_b  = (const float*)d_in[9];
    const float* pos_w    = (const float*)d_in[10];
    const float* pos_b    = (const float*)d_in[11];
    const float* q_w      = (const float*)d_in[12];
    const float* q_b      = (const float*)d_in[13];
    const float* k_w      = (const float*)d_in[14];
    const float* k_b      = (const float*)d_in[15];
    const float* out_w    = (const float*)d_in[16];
    const float* out_b    = (const float*)d_in[17];
    float* ws = (float*)d_ws;

    float* roi_emb      = ws + O_ROIEMB;
    float* rank_feat    = ws + O_RANKF;
    int*   rank_idx     = (int*)(ws + O_RANKIDX);
    float* sorted_score = ws + O_SSCORE;
    float* sorted_boxes = ws + O_SBOX;
    float* emb_feat     = ws + O_EMB;
    float* embT         = ws + O_EMBT;
    float* att          = ws + O_ATT;
    unsigned short* lwb = (unsigned short*)(ws + O_LW);

    k_roi_emb<<<dim3(B_*NB_), dim3(128), 0, stream>>>(roi_feat, roi_w, roi_b, roi_emb);
    k_rank_feat<<<dim3(FN_), dim3(128), 0, stream>>>(rank_w, rank_b, rank_feat);
    k_topk<<<dim3(B_*C_), dim3(512), 0, stream>>>(scores, rank_idx, sorted_score);
    k_gather<<<dim3(B_*FN_*C_), dim3(128), 0, stream>>>(rank_idx, roi_emb, rank_feat,
                                                        pdeltas, pboxes, emb_feat, sorted_boxes);
    k_transpose<<<dim3(B_*C_), dim3(256), 0, stream>>>(emb_feat, embT);

    for (int b = 0; b < B_; ++b) {
        for (int c0 = 0; c0 < C_; c0 += CC_) {
            k_pos2<<<dim3(CC_*16), dim3(256), 0, stream>>>(sorted_boxes, pos_w, pos_b, lwb, b, c0);
            k_attn<<<dim3(CC_*G_), dim3(1024), 0, stream>>>(embT, q_w, q_b, k_w, k_b,
                                                            out_w, out_b, lwb, att, b, c0);
        }
    }

    k_final<<<dim3(B_*FN_*C_), dim3(128), 0, stream>>>(emb_feat, att, logit_w, logit_b,
                                                       sorted_score, d_out ? (float*)d_out : nullptr);
}

// Round 4
// 396.990 us; speedup vs baseline: 4.6016x; 2.4489x over previous
//
#include <hip/hip_runtime.h>
#include <math.h>

#define B_    2
#define NB_   512
#define C_    80
#define FEAT_ 1024
#define FN_   128
#define FC_   128
#define PE_   64
#define G_    16
#define DQ_   64
#define EO_   8
#define NT_   3
#define CC_   16          // classes per chunk
#define NCHUNK_ 10
#define SCALE_CLAMP_ 4.135166556742356f

typedef __attribute__((ext_vector_type(8))) short bf16x8;
typedef __attribute__((ext_vector_type(4))) float f32x4;

// ---- workspace layout (float offsets) ----
#define O_ROIEMB  ((size_t)0)                                   // 1024*128
#define O_RANKF   (O_ROIEMB + (size_t)(B_*NB_)*FC_)             // 128*128
#define O_RANKIDX (O_RANKF + (size_t)FN_*FC_)                   // B*128*80 (int)
#define O_SSCORE  (O_RANKIDX + (size_t)B_*FN_*C_)               // B*128*80
#define O_SBOX    (O_SSCORE + (size_t)B_*FN_*C_)                // B*128*80*4
#define O_EMB     (O_SBOX + (size_t)B_*FN_*C_*4)                // B*128*80*128
#define O_ATT     (O_EMB + (size_t)B_*FN_*C_*FC_)               // B*128*80*128
#define O_LW0     (O_ATT + (size_t)B_*FN_*C_*FC_)               // CC*128*16*128 ushort
#define O_LW1     (O_LW0 + (size_t)CC_*FN_*G_*FN_/2)

__device__ __forceinline__ float bf2f(unsigned short u) {
    return __uint_as_float(((unsigned int)u) << 16);
}
__device__ __forceinline__ unsigned short f2bf(float f) {
    unsigned int x = __float_as_uint(f);
    unsigned int r = (x + 0x7fff + ((x >> 16) & 1)) >> 16;   // RNE
    return (unsigned short)r;
}

// ============ roi_emb = roi_feat @ roi_w + roi_b ============
__global__ __launch_bounds__(128) void k_roi_emb(const float* __restrict__ roi_feat,
                                                 const float* __restrict__ roi_w,
                                                 const float* __restrict__ roi_b,
                                                 float* __restrict__ roi_emb)
{
    __shared__ float row[FEAT_];
    int r = blockIdx.x;
    for (int i = threadIdx.x; i < FEAT_; i += 128) row[i] = roi_feat[(size_t)r*FEAT_ + i];
    __syncthreads();
    int j = threadIdx.x;
    float acc = 0.f;
    for (int k = 0; k < FEAT_; ++k) acc += row[k] * roi_w[(size_t)k*FC_ + j];
    roi_emb[(size_t)r*FC_ + j] = acc + roi_b[j];
}

// ============ rank_feat ============
__global__ __launch_bounds__(128) void k_rank_feat(const float* __restrict__ rank_w,
                                                   const float* __restrict__ rank_b,
                                                   float* __restrict__ rank_feat)
{
    __shared__ float emb[FEAT_];
    int n = blockIdx.x;
    for (int i = threadIdx.x; i < FEAT_/2; i += 128) {
        float dim = powf(1000.0f, (2.0f/(float)FEAT_) * (float)i);
        float dv = (float)n / dim;
        emb[i] = sinf(dv);
        emb[i + FEAT_/2] = cosf(dv);
    }
    __syncthreads();
    int j = threadIdx.x;
    float acc = 0.f;
    for (int k = 0; k < FEAT_; ++k) acc += emb[k] * rank_w[(size_t)k*FC_ + j];
    rank_feat[(size_t)n*FC_ + j] = acc + rank_b[j];
}

// ============ softmax over boxes + stable top-128 rank ============
__global__ __launch_bounds__(512) void k_topk(const float* __restrict__ scores,
                                              int* __restrict__ rank_idx,
                                              float* __restrict__ sorted_score)
{
    int b = blockIdx.x / C_, c = blockIdx.x % C_;
    __shared__ float p[NB_];
    __shared__ float red[NB_];
    int i = threadIdx.x;
    float s = scores[(size_t)(b*NB_ + i)*(C_+1) + c];
    red[i] = s; __syncthreads();
    for (int o = 256; o > 0; o >>= 1) { if (i < o) red[i] = fmaxf(red[i], red[i+o]); __syncthreads(); }
    float mx = red[0]; __syncthreads();
    float e = expf(s - mx);
    red[i] = e; __syncthreads();
    for (int o = 256; o > 0; o >>= 1) { if (i < o) red[i] += red[i+o]; __syncthreads(); }
    float sum = red[0]; __syncthreads();
    float pi = e / sum;
    p[i] = pi; __syncthreads();
    int rank = 0;
    for (int j = 0; j < NB_; ++j) {
        float pj = p[j];
        rank += (pj > pi) || (pj == pi && j < i);
    }
    if (rank < FN_) {
        rank_idx[(size_t)(b*FN_ + rank)*C_ + c] = i;
        sorted_score[(size_t)(b*FN_ + rank)*C_ + c] = pi;
    }
}

// ============ gather emb_feat + refined sorted boxes ============
__global__ __launch_bounds__(128) void k_gather(const int* __restrict__ rank_idx,
                                                const float* __restrict__ roi_emb,
                                                const float* __restrict__ rank_feat,
                                                const float* __restrict__ pdeltas,
                                                const float* __restrict__ pboxes,
                                                float* __restrict__ emb_feat,
                                                float* __restrict__ sorted_boxes)
{
    int item = blockIdx.x;          // (b*128+n)*80 + c
    int c = item % C_;
    int bn = item / C_;
    int n = bn & (FN_-1);
    int b = bn >> 7;
    int idx = rank_idx[item];
    int row = b*NB_ + idx;
    int d = threadIdx.x;
    emb_feat[(size_t)item*FC_ + d] = roi_emb[(size_t)row*FC_ + d] + rank_feat[(size_t)n*FC_ + d];
    if (d == 0) {
        float x1 = pboxes[row*4+0], y1 = pboxes[row*4+1], x2 = pboxes[row*4+2], y2 = pboxes[row*4+3];
        float w = x2 - x1, h = y2 - y1;
        float cx = x1 + 0.5f*w, cy = y1 + 0.5f*h;
        const float* dl = pdeltas + (size_t)row*(C_*4) + c*4;
        float dx = dl[0]/10.0f, dy = dl[1]/10.0f;
        float dw = fminf(dl[2]/5.0f, SCALE_CLAMP_);
        float dh = fminf(dl[3]/5.0f, SCALE_CLAMP_);
        float pcx = dx*w + cx, pcy = dy*h + cy;
        float pw = expf(dw)*w, ph = expf(dh)*h;
        float* ob = sorted_boxes + (size_t)item*4;
        ob[0] = pcx - 0.5f*pw; ob[1] = pcy - 0.5f*ph;
        ob[2] = pcx + 0.5f*pw; ob[3] = pcy + 0.5f*ph;
    }
}

// ============ prior w (pre-log, clamped), all 16 groups, bf16 ============
// grid: CC_*32 (cl = bid>>5, n-quad = bid&31), 256 threads.
// lw layout: [cl][n][g][m] bf16
__global__ __launch_bounds__(256) void k_pos2(const float* __restrict__ sorted_boxes,
                                              const float* __restrict__ pos_w,
                                              const float* __restrict__ pos_b,
                                              unsigned short* __restrict__ lw,
                                              int b, int c0)
{
    const int cl  = blockIdx.x >> 5;
    const int n0  = (blockIdx.x & 31) * 4;
    const int c   = c0 + cl;
    const int t   = threadIdx.x;
    const int m   = t & 127;
    const int nh  = t >> 7;

    __shared__ float geomL[FN_][6];
    __shared__ float pwL[PE_*G_];
    __shared__ float pbL[G_];
    __shared__ float sdimL[8];
    __shared__ unsigned short wtile[2*G_*FN_];   // 8 KB

    for (int i = t; i < PE_*G_; i += 256) pwL[i] = pos_w[i];
    if (t < G_) pbL[t] = pos_b[t];
    if (t >= 16 && t < 24) sdimL[t-16] = 1.0f / powf(1000.0f, 0.125f*(float)(t-16));
    if (t < FN_) {
        const float* bx = sorted_boxes + (((size_t)(b*FN_ + t))*C_ + c)*4;
        float x1 = bx[0], y1 = bx[1], x2 = bx[2], y2 = bx[3];
        float w = x2 - x1 + 1.0f;
        float h = y2 - y1 + 1.0f;
        geomL[t][0] = 0.5f*(x1+x2);
        geomL[t][1] = 0.5f*(y1+y2);
        geomL[t][2] = w;
        geomL[t][3] = h;
        geomL[t][4] = __logf(w);
        geomL[t][5] = __logf(h);
    }
    __syncthreads();

    for (int s = 0; s < 2; ++s) {
        const int n = n0 + s*2 + nh;
        float pm[4];
        {
            float cxn = geomL[n][0], cyn = geomL[n][1];
            float rwn = 1.0f/geomL[n][2], rhn = 1.0f/geomL[n][3];
            pm[0] = __logf(fmaxf(fabsf((cxn - geomL[m][0]) * rwn), 1e-3f)) * 100.0f;
            pm[1] = __logf(fmaxf(fabsf((cyn - geomL[m][1]) * rhn), 1e-3f)) * 100.0f;
            pm[2] = (geomL[n][4] - geomL[m][4]) * 100.0f;
            pm[3] = (geomL[n][5] - geomL[m][5]) * 100.0f;
        }
        float acc[G_];
        #pragma unroll
        for (int g = 0; g < G_; ++g) acc[g] = pbL[g];
        #pragma unroll 1
        for (int r = 0; r < 8; ++r) {
            float inv = sdimL[r];
            #pragma unroll
            for (int f = 0; f < 4; ++f) {
                float a = pm[f] * inv;
                float sv, cv;
                __sincosf(a, &sv, &cv);
                const float* ws_ = &pwL[(f*16 + r)*G_];
                const float* wc_ = &pwL[(f*16 + 8 + r)*G_];
                #pragma unroll
                for (int g = 0; g < G_; ++g) acc[g] += sv*ws_[g] + cv*wc_[g];
            }
        }
        #pragma unroll
        for (int g = 0; g < G_; ++g) {
            float w = fmaxf(fmaxf(acc[g], 0.0f), 1e-6f);
            wtile[(nh*G_ + g)*FN_ + m] = f2bf(w);
        }
        __syncthreads();
        {
            const size_t base4 = ((size_t)(cl*FN_ + n0 + s*2)) * 256;  // float4 units
            const float4* srcv = (const float4*)wtile;
            float4* dstv = (float4*)lw;
            dstv[base4 + t]       = srcv[t];
            dstv[base4 + t + 256] = srcv[t + 256];
        }
        __syncthreads();
    }
}

// ============ MFMA attention per (class-in-chunk, group) ============
// LDS arena offsets (bytes)
#define FT_OFF   0        // ft bf16 [128n][128d] swz   32 KB  (aliased by P later)
#define QL_OFF   32768    // q bf16 [128n][64dq] swz    16 KB
#define KL_OFF   49152    // k bf16 [128m][64dq] swz    16 KB
#define WT_OFF   65536    // W^T bf16 [144r][128d] swz  36 KB (aliased by affL)
#define AFF_OFF  65536    // aff f32 [128][133]         68.1 KB
#define VT_OFF   133632   // V'^T bf16 [16e][128m] swz  4 KB
#define BIAS_OFF 137728   // 128 f32
#define SMEM_SZ  138240

// 16B-granule swizzled byte addresses (row stride 256B, 16 granules)
#define ADDR256(row, gr)  ((row)*256 + ((((gr) ^ ((row)&15))) << 4))
// row stride 128B, 8 granules
#define ADDR128(row, gr)  ((row)*128 + ((((gr) ^ ((row)&7))) << 4))

__global__ __launch_bounds__(1024) void k_attn(const float* __restrict__ emb_feat,
                                               const float* __restrict__ q_w, const float* __restrict__ q_b,
                                               const float* __restrict__ k_w, const float* __restrict__ k_b,
                                               const float* __restrict__ out_w, const float* __restrict__ out_b,
                                               const unsigned short* __restrict__ lw,
                                               float* __restrict__ att,
                                               int b, int c0)
{
    const int cl = blockIdx.x & 15;        // same class -> same XCD (bid%8)
    const int g  = blockIdx.x >> 4;
    const int c  = c0 + cl;
    const int t  = threadIdx.x;
    const int wave = t >> 6;
    const int lane = t & 63;
    const int lr = lane & 15;
    const int lh = lane >> 4;              // 0..3

    __shared__ char smem[SMEM_SZ];
    float* biasL = (float*)(smem + BIAS_OFF);
    float* affF  = (float*)(smem + AFF_OFF);

    // ================= P0: staging =================
    // ft: emb rows -> bf16 swz [n][d]
    for (int s = 0; s < 4; ++s) {
        int fi = t + s*1024;
        int n  = fi >> 5;
        int d4 = (fi & 31) << 2;
        float4 v = *(const float4*)(emb_feat + ((size_t)(b*FN_ + n)*C_ + c)*FC_ + d4);
        char* dst = smem + FT_OFF + ADDR256(n, d4 >> 3) + ((d4 >> 2) & 1)*8;
        *(uint2*)dst = make_uint2((unsigned)f2bf(v.x) | ((unsigned)f2bf(v.y) << 16),
                                  (unsigned)f2bf(v.z) | ((unsigned)f2bf(v.w) << 16));
    }
    // WT rows 0..127: q_w / k_w column slices, transposed, bf16 swz
    for (int s = 0; s < 2; ++s) {
        int id = t + s*1024;
        int r  = id & 127;
        int g8 = id >> 7;                  // 0..15
        const float* src = (r < 64) ? (q_w + (size_t)(g8*8)*1024 + g*DQ_ + r)
                                    : (k_w + (size_t)(g8*8)*1024 + g*DQ_ + (r-64));
        unsigned short u[8];
        #pragma unroll
        for (int j = 0; j < 8; ++j) u[j] = f2bf(src[(size_t)j*1024]);
        char* dst = smem + WT_OFF + ADDR256(r, g8);
        *(uint4*)dst = make_uint4((unsigned)u[0] | ((unsigned)u[1] << 16),
                                  (unsigned)u[2] | ((unsigned)u[3] << 16),
                                  (unsigned)u[4] | ((unsigned)u[5] << 16),
                                  (unsigned)u[6] | ((unsigned)u[7] << 16));
    }
    // WT rows 128..135: Wo^T
    if (t < 128) {
        int e  = t & 7;
        int g8 = t >> 3;
        const float* src = out_w + (size_t)g*FC_*EO_ + (size_t)(g8*8)*EO_ + e;
        unsigned short u[8];
        #pragma unroll
        for (int j = 0; j < 8; ++j) u[j] = f2bf(src[(size_t)j*EO_]);
        int r = 128 + e;
        char* dst = smem + WT_OFF + ADDR256(r, g8);
        *(uint4*)dst = make_uint4((unsigned)u[0] | ((unsigned)u[1] << 16),
                                  (unsigned)u[2] | ((unsigned)u[3] << 16),
                                  (unsigned)u[4] | ((unsigned)u[5] << 16),
                                  (unsigned)u[6] | ((unsigned)u[7] << 16));
    }
    // zero dead WT rows 136..143 and V'T rows 8..15
    if (t >= 256 && t < 512) {
        int i = t - 256;
        *(uint2*)(smem + WT_OFF + 136*256 + i*8) = make_uint2(0u, 0u);
    }
    if (t >= 512 && t < 768) {
        int i = t - 512;
        *(uint2*)(smem + VT_OFF + 8*256 + i*8) = make_uint2(0u, 0u);
    }
    // biases
    if (t >= 128 && t < 256) {
        int r = t - 128;
        biasL[r] = (r < 64) ? q_b[g*DQ_ + r] : k_b[g*DQ_ + (r-64)];
    }
    __syncthreads();

    // ================= P1: proj MFMA  D[r][n] = WT . ft^T =================
    {
        const int rb = (wave >> 2) * 32;
        const int nb = (wave & 3) * 32;
        f32x4 acc00 = {0,0,0,0}, acc01 = {0,0,0,0}, acc10 = {0,0,0,0}, acc11 = {0,0,0,0};
        f32x4 accV  = {0,0,0,0};
        #pragma unroll
        for (int ks = 0; ks < 4; ++ks) {
            int soff = ((ks*4 + lh) ^ lr) << 4;
            bf16x8 a0 = *(const bf16x8*)(smem + WT_OFF + (rb + lr)*256 + soff);
            bf16x8 a1 = *(const bf16x8*)(smem + WT_OFF + (rb + 16 + lr)*256 + soff);
            bf16x8 b0 = *(const bf16x8*)(smem + FT_OFF + (nb + lr)*256 + soff);
            bf16x8 b1 = *(const bf16x8*)(smem + FT_OFF + (nb + 16 + lr)*256 + soff);
            acc00 = __builtin_amdgcn_mfma_f32_16x16x32_bf16(a0, b0, acc00, 0, 0, 0);
            acc01 = __builtin_amdgcn_mfma_f32_16x16x32_bf16(a0, b1, acc01, 0, 0, 0);
            acc10 = __builtin_amdgcn_mfma_f32_16x16x32_bf16(a1, b0, acc10, 0, 0, 0);
            acc11 = __builtin_amdgcn_mfma_f32_16x16x32_bf16(a1, b1, acc11, 0, 0, 0);
            if (wave < 8) {
                bf16x8 av = *(const bf16x8*)(smem + WT_OFF + (128 + lr)*256 + soff);
                bf16x8 bv = *(const bf16x8*)(smem + FT_OFF + (wave*16 + lr)*256 + soff);
                accV = __builtin_amdgcn_mfma_f32_16x16x32_bf16(av, bv, accV, 0, 0, 0);
            }
        }
        // write q/k tiles: D row r -> (q|k)[n][dq]
        #pragma unroll
        for (int ti = 0; ti < 2; ++ti) {
            #pragma unroll
            for (int tj = 0; tj < 2; ++tj) {
                f32x4 a = (ti == 0) ? (tj == 0 ? acc00 : acc01) : (tj == 0 ? acc10 : acc11);
                int r0 = rb + ti*16 + lh*4;
                int n  = nb + tj*16 + lr;
                float v0 = a[0] + biasL[r0+0];
                float v1 = a[1] + biasL[r0+1];
                float v2 = a[2] + biasL[r0+2];
                float v3 = a[3] + biasL[r0+3];
                int dq0 = r0 & 63;
                int off = (r0 < 64 ? QL_OFF : KL_OFF);
                char* dst = smem + off + ADDR128(n, dq0 >> 3) + ((dq0 >> 2) & 1)*8;
                *(uint2*)dst = make_uint2((unsigned)f2bf(v0) | ((unsigned)f2bf(v1) << 16),
                                          (unsigned)f2bf(v2) | ((unsigned)f2bf(v3) << 16));
            }
        }
        // V' tile rows 128..143 -> V'T[e][m] bf16
        if (wave < 8 && lh < 2) {
            int m = wave*16 + lr;
            #pragma unroll
            for (int reg = 0; reg < 4; ++reg) {
                int e = lh*4 + reg;   // 0..7
                char* dst = smem + VT_OFF + (e)*256 + ((((m >> 3) ^ e)) << 4) + (m & 7)*2;
                *(unsigned short*)dst = f2bf(accV[reg]);
            }
        }
    }
    __syncthreads();

    // ================= P2: aff MFMA  aff[n][m] = q . k^T =================
    {
        const int nb = (wave >> 2) * 32;
        const int mb = (wave & 3) * 32;
        f32x4 acc00 = {0,0,0,0}, acc01 = {0,0,0,0}, acc10 = {0,0,0,0}, acc11 = {0,0,0,0};
        #pragma unroll
        for (int ks = 0; ks < 2; ++ks) {
            int soff = ((ks*4 + lh) ^ (lr & 7)) << 4;
            bf16x8 a0 = *(const bf16x8*)(smem + QL_OFF + (nb + lr)*128 + soff);
            bf16x8 a1 = *(const bf16x8*)(smem + QL_OFF + (nb + 16 + lr)*128 + soff);
            bf16x8 b0 = *(const bf16x8*)(smem + KL_OFF + (mb + lr)*128 + soff);
            bf16x8 b1 = *(const bf16x8*)(smem + KL_OFF + (mb + 16 + lr)*128 + soff);
            acc00 = __builtin_amdgcn_mfma_f32_16x16x32_bf16(a0, b0, acc00, 0, 0, 0);
            acc01 = __builtin_amdgcn_mfma_f32_16x16x32_bf16(a0, b1, acc01, 0, 0, 0);
            acc10 = __builtin_amdgcn_mfma_f32_16x16x32_bf16(a1, b0, acc10, 0, 0, 0);
            acc11 = __builtin_amdgcn_mfma_f32_16x16x32_bf16(a1, b1, acc11, 0, 0, 0);
        }
        #pragma unroll
        for (int ti = 0; ti < 2; ++ti) {
            #pragma unroll
            for (int tj = 0; tj < 2; ++tj) {
                f32x4 a = (ti == 0) ? (tj == 0 ? acc00 : acc01) : (tj == 0 ? acc10 : acc11);
                int n0 = nb + ti*16 + lh*4;
                int m  = mb + tj*16 + lr;
                #pragma unroll
                for (int reg = 0; reg < 4; ++reg)
                    affF[(n0 + reg)*133 + m] = a[reg];
            }
        }
    }
    __syncthreads();

    // ================= P3: softmax rows (prior fused), write P bf16 over ft =================
    {
        const int row = t >> 3;
        const int lp  = t & 7;
        const int m0  = lp * 16;
        const unsigned short* lwrow = lw + (((size_t)cl*FN_ + row)*G_ + g)*FN_ + m0;
        float v[16];
        float mx = -INFINITY;
        #pragma unroll
        for (int j = 0; j < 16; ++j) {
            float val = affF[row*133 + m0 + j]*0.125f + __logf(bf2f(lwrow[j]));
            v[j] = val;
            mx = fmaxf(mx, val);
        }
        #pragma unroll
        for (int s = 1; s < 8; s <<= 1) mx = fmaxf(mx, __shfl_xor(mx, s, 8));
        float sum = 0.f;
        #pragma unroll
        for (int j = 0; j < 16; ++j) { v[j] = __expf(v[j] - mx); sum += v[j]; }
        #pragma unroll
        for (int s = 1; s < 8; s <<= 1) sum += __shfl_xor(sum, s, 8);
        float rs = 1.0f / sum;
        unsigned short u[16];
        #pragma unroll
        for (int j = 0; j < 16; ++j) u[j] = f2bf(v[j] * rs);
        char* d0 = smem + FT_OFF + ADDR256(row, lp*2);
        char* d1 = smem + FT_OFF + ADDR256(row, lp*2 + 1);
        *(uint4*)d0 = make_uint4((unsigned)u[0] | ((unsigned)u[1] << 16),
                                 (unsigned)u[2] | ((unsigned)u[3] << 16),
                                 (unsigned)u[4] | ((unsigned)u[5] << 16),
                                 (unsigned)u[6] | ((unsigned)u[7] << 16));
        *(uint4*)d1 = make_uint4((unsigned)u[8]  | ((unsigned)u[9]  << 16),
                                 (unsigned)u[10] | ((unsigned)u[11] << 16),
                                 (unsigned)u[12] | ((unsigned)u[13] << 16),
                                 (unsigned)u[14] | ((unsigned)u[15] << 16));
    }
    __syncthreads();

    // ================= P4: att = P @ V'  (MFMA), write global =================
    if (wave < 8) {
        const int tb = wave * 16;
        f32x4 acc = {0,0,0,0};
        #pragma unroll
        for (int ks = 0; ks < 4; ++ks) {
            int soff = ((ks*4 + lh) ^ lr) << 4;
            bf16x8 a = *(const bf16x8*)(smem + FT_OFF + (tb + lr)*256 + soff);
            bf16x8 bv = *(const bf16x8*)(smem + VT_OFF + lr*256 + soff);
            acc = __builtin_amdgcn_mfma_f32_16x16x32_bf16(a, bv, acc, 0, 0, 0);
        }
        if (lr < 8) {
            float ob = out_b[g*EO_ + lr];
            #pragma unroll
            for (int reg = 0; reg < 4; ++reg) {
                int n = tb + lh*4 + reg;
                att[((size_t)(b*FN_ + n)*C_ + c)*FC_ + g*EO_ + lr] = acc[reg] + ob;
            }
        }
    }
}

// ============ final ============
__global__ __launch_bounds__(128) void k_final(const float* __restrict__ emb_feat,
                                               const float* __restrict__ att,
                                               const float* __restrict__ logit_w,
                                               const float* __restrict__ logit_b,
                                               const float* __restrict__ sorted_score,
                                               float* __restrict__ out)
{
    int item = blockIdx.x;
    int d = threadIdx.x;
    __shared__ float af[FC_];
    float v = emb_feat[(size_t)item*FC_ + d] + att[(size_t)item*FC_ + d];
    af[d] = fmaxf(v, 0.f);
    __syncthreads();
    if (d < NT_) {
        float acc = logit_b[d];
        for (int k = 0; k < FC_; ++k) acc += af[k] * logit_w[(size_t)k*NT_ + d];
        float s = 1.f / (1.f + expf(-acc));
        out[(size_t)item*NT_ + d] = s * sorted_score[item];
    }
}

extern "C" void kernel_launch(void* const* d_in, const int* in_sizes, int n_in,
                              void* d_out, int out_size, void* d_ws, size_t ws_size,
                              hipStream_t stream) {
    (void)in_sizes; (void)n_in; (void)out_size; (void)ws_size;
    const float* roi_feat = (const float*)d_in[0];
    const float* scores   = (const float*)d_in[1];
    const float* pdeltas  = (const float*)d_in[2];
    const float* pboxes   = (const float*)d_in[3];
    const float* roi_w    = (const float*)d_in[4];
    const float* roi_b    = (const float*)d_in[5];
    const float* rank_w   = (const float*)d_in[6];
    const float* rank_b   = (const float*)d_in[7];
    const float* logit_w  = (const float*)d_in[8];
    const float* logit_b  = (const float*)d_in[9];
    const float* pos_w    = (const float*)d_in[10];
    const float* pos_b    = (const float*)d_in[11];
    const float* q_w      = (const float*)d_in[12];
    const float* q_b      = (const float*)d_in[13];
    const float* k_w      = (const float*)d_in[14];
    const float* k_b      = (const float*)d_in[15];
    const float* out_w    = (const float*)d_in[16];
    const float* out_b    = (const float*)d_in[17];
    float* ws = (float*)d_ws;

    float* roi_emb      = ws + O_ROIEMB;
    float* rank_feat    = ws + O_RANKF;
    int*   rank_idx     = (int*)(ws + O_RANKIDX);
    float* sorted_score = ws + O_SSCORE;
    float* sorted_boxes = ws + O_SBOX;
    float* emb_feat     = ws + O_EMB;
    float* att          = ws + O_ATT;
    unsigned short* lwb[2] = { (unsigned short*)(ws + O_LW0), (unsigned short*)(ws + O_LW1) };

    k_roi_emb<<<dim3(B_*NB_), dim3(128), 0, stream>>>(roi_feat, roi_w, roi_b, roi_emb);
    k_rank_feat<<<dim3(FN_), dim3(128), 0, stream>>>(rank_w, rank_b, rank_feat);
    k_topk<<<dim3(B_*C_), dim3(512), 0, stream>>>(scores, rank_idx, sorted_score);
    k_gather<<<dim3(B_*FN_*C_), dim3(128), 0, stream>>>(rank_idx, roi_emb, rank_feat,
                                                        pdeltas, pboxes, emb_feat, sorted_boxes);

    // chunk i: b = i/5, c0 = (i%5)*16 ; lw double-buffered, pos2(i+1) overlaps attn(i)
    k_pos2<<<dim3(CC_*32), dim3(256), 0, stream>>>(sorted_boxes, pos_w, pos_b, lwb[0], 0, 0);
    for (int i = 0; i < NCHUNK_; ++i) {
        int b = i / 5, c0 = (i % 5) * 16;
        if (i + 1 < NCHUNK_) {
            int b2 = (i+1) / 5, c02 = ((i+1) % 5) * 16;
            k_pos2<<<dim3(CC_*32), dim3(256), 0, stream>>>(sorted_boxes, pos_w, pos_b,
                                                           lwb[(i+1) & 1], b2, c02);
        }
        k_attn<<<dim3(CC_*G_), dim3(1024), 0, stream>>>(emb_feat, q_w, q_b, k_w, k_b,
                                                        out_w, out_b, lwb[i & 1], att, b, c0);
    }

    k_final<<<dim3(B_*FN_*C_), dim3(128), 0, stream>>>(emb_feat, att, logit_w, logit_b,
                                                       sorted_score, d_out ? (float*)d_out : nullptr);
}